// Round 10
// baseline (171.841 us; speedup 1.0000x reference)
//
#include <hip/hip_runtime.h>

// BurstSnn: 32-step burst-encoder + 2-layer LIF SNN, B=16384, D=187, H=50, C=5.
// One wave per batch element; 16 waves/block share one LDS weight copy.
// R9 = R8 (best, 115us; LDS-issue wall at ~94%) + VMEM OFFLOAD: per phase,
// 2 streams read Wt1 rows from LDS and 1 stream (groups 4/5) reads the SAME
// padded layout from a d_ws global copy (L1/L2-cached) -> the binding LDS
// pipe drops from 3 to 2 reads/trip while the idle VMEM pipe absorbs the
// third. Values/order bit-identical. Prep kernel rebuilds d_ws every launch
// (harness re-poisons d_ws); host falls back to pure-LDS kernel if ws_size
// is too small.

constexpr int D = 187;
constexpr int H = 50;
constexpr int C = 5;
constexpr int T = 32;
constexpr int WPB = 16;        // waves per block
constexpr int ROWS1 = 193;     // rows rd = 33*(d>>5) + (d&31) + 1; rd=33g zero
constexpr int RS = 64;         // floats per Wt1 row (256 B)
constexpr int WG_BYTES = ROWS1 * RS * 4;   // 49408

__device__ __forceinline__ int v_ffbl(unsigned int m) {  // -1 when m == 0
    int r;
    asm("v_ffbl_b32 %0, %1" : "=v"(r) : "v"(m));
    return r;
}

// ---- prep: build the padded split-pair W1^T layout in global scratch -------
__global__ void prep_wg(const float* __restrict__ W1, float* __restrict__ Wg) {
    int idx = blockIdx.x * 1024 + threadIdx.x;
    if (idx >= ROWS1 * RS) return;
    int rd = idx >> 6, j = idx & 63;
    int g = rd / 33;
    bool zrow = (rd == 33 * g);
    int d = rd - 1 - g;
    int l = j >> 1;
    int h = (j & 1) ? (l + 25) : l;
    float v = 0.f;
    if (!zrow && l < 25 && d >= 0 && d < D) v = W1[h * D + d];
    Wg[idx] = v;
}

// ---- main kernel (templated on whether groups 4/5 come from global) --------
template <bool USE_VMEM>
__global__ __launch_bounds__(1024, 8)
void burst_snn_kernel(const float* __restrict__ x,
                      const float* __restrict__ W1,
                      const float* __restrict__ W2,
                      const float* __restrict__ Wg,
                      float* __restrict__ out, int B) {
    // Wt1 row layout (split-pair): floats {2l,2l+1} = {W[h=l], W[h=l+25]}, l<25.
    __shared__ float Wt1[ROWS1 * RS];   // 12352 floats = 48.25 KB
    // Wt2: 64 rows x 16 floats. row 0: zeros; rows 1..25: h=0..24;
    // row 26: zeros; rows 27..51: h=25..49; rest zeros. cols 5..15 zero pad.
    __shared__ float Wt2[1024];         // 4 KB

    const int tid = threadIdx.x;
    for (int idx = tid; idx < ROWS1 * RS; idx += 1024) {
        int rd = idx >> 6, j = idx & 63;
        int g = rd / 33;
        bool zrow = (rd == 33 * g);
        int d = rd - 1 - g;
        int l = j >> 1;
        int h = (j & 1) ? (l + 25) : l;
        float v = 0.f;
        if (!zrow && l < 25) v = W1[h * D + d];
        Wt1[idx] = v;
    }
    {
        int r = tid >> 4, c = tid & 15;   // tid covers all 1024
        int h = -1;
        if (r >= 1 && r <= 25) h = r - 1;
        else if (r >= 27 && r <= 51) h = r - 2;
        float v = 0.f;
        if (h >= 0 && c < C) v = W2[c * H + h];
        Wt2[tid] = v;
    }
    __syncthreads();

    const int lane = tid & 63;
    const int b = blockIdx.x * WPB + (tid >> 6);
    const bool active = b < B;
    const bool isLo = lane < 32;
    const int laneHalf = lane & 31;
    const int laneOff2 = laneHalf * 2;   // float2 slot within a Wt1 row

    // L1 per-group base pointers, +1 row folded in: addr(f) = base + f*64;
    // f = -1 (exhausted stream) -> zero row 33g.
    const float* gbase0 = Wt1 + ((33 * 0 + 1) << 6) + laneOff2;
    const float* gbase1 = Wt1 + ((33 * 1 + 1) << 6) + laneOff2;
    const float* gbase2 = Wt1 + ((33 * 2 + 1) << 6) + laneOff2;
    const float* gbase3 = Wt1 + ((33 * 3 + 1) << 6) + laneOff2;
    // Groups 4/5: LDS or global (d_ws copy) depending on USE_VMEM.
    const float* gbase4 = (USE_VMEM ? Wg : Wt1) + ((33 * 4 + 1) << 6) + laneOff2;
    const float* gbase5 = (USE_VMEM ? Wg : Wt1) + ((33 * 5 + 1) << 6) + laneOff2;

    // L2 quarter-wave setup: quarter q = lane>>4 scans {lo_t,hi_t,lo_u,hi_u}.
    const int q = lane >> 4;
    const bool hiQ = (q & 1) != 0;
    const float* base2 = Wt2 + ((hiQ ? 27 : 1) << 4) + (lane & 15);

    // Encoder registers: dims lane, lane+64, lane+128 (3rd valid for lane<59)
    float r0 = 0.f, r1 = 0.f, r2 = 0.f;
    if (active) {
        const float* xb = x + (size_t)b * D;
        r0 = xb[lane];
        r1 = xb[64 + lane];
        if (lane < D - 128) r2 = xb[128 + lane];
    }
    float th0 = 0.125f, th1 = 0.125f, th2 = 0.125f;
    float mem1x = 0.f, mem1y = 0.f;  // lanes 0..24: h = lane / h = lane+25
    float mem2 = 0.f;                // lanes 0..4: c = lane
    int cnt = 0;

    float* outSpk = out;                     // [T][B][C]
    float* outCnt = out + (size_t)T * B * C; // [B]

    unsigned int ga[6], gb[6];

    for (int t = 0; t < T; t += 2) {
        // --- two encoder steps (exact fp32 sequence), masks for t and t+1
        {
            bool s0 = r0 >= th0, s1 = r1 >= th1, s2 = r2 >= th2;
            r0 -= s0 ? th0 : 0.f; th0 = s0 ? th0 + th0 : 0.125f;
            r1 -= s1 ? th1 : 0.f; th1 = s1 ? th1 + th1 : 0.125f;
            r2 -= s2 ? th2 : 0.f; th2 = s2 ? th2 + th2 : 0.125f;
            cnt += (int)s0 + (int)s1 + (int)s2;
            unsigned long long B0 = __ballot(s0), B1 = __ballot(s1), B2 = __ballot(s2);
            ga[0] = (unsigned int)B0; ga[1] = (unsigned int)(B0 >> 32);
            ga[2] = (unsigned int)B1; ga[3] = (unsigned int)(B1 >> 32);
            ga[4] = (unsigned int)B2; ga[5] = (unsigned int)(B2 >> 32);
        }
        {
            bool s0 = r0 >= th0, s1 = r1 >= th1, s2 = r2 >= th2;
            r0 -= s0 ? th0 : 0.f; th0 = s0 ? th0 + th0 : 0.125f;
            r1 -= s1 ? th1 : 0.f; th1 = s1 ? th1 + th1 : 0.125f;
            r2 -= s2 ? th2 : 0.f; th2 = s2 ? th2 + th2 : 0.125f;
            cnt += (int)s0 + (int)s1 + (int)s2;
            unsigned long long B0 = __ballot(s0), B1 = __ballot(s1), B2 = __ballot(s2);
            gb[0] = (unsigned int)B0; gb[1] = (unsigned int)(B0 >> 32);
            gb[2] = (unsigned int)B1; gb[3] = (unsigned int)(B1 >> 32);
            gb[4] = (unsigned int)B2; gb[5] = (unsigned int)(B2 >> 32);
        }

        // Per-lane masks: lanes<32 step t, lanes>=32 step t+1
        unsigned int vm0 = isLo ? ga[0] : gb[0];
        unsigned int vm1 = isLo ? ga[1] : gb[1];
        unsigned int vm2 = isLo ? ga[2] : gb[2];
        unsigned int vm3 = isLo ? ga[3] : gb[3];
        unsigned int vm4 = isLo ? ga[4] : gb[4];
        unsigned int vm5 = isLo ? ga[5] : gb[5];

        float cx0 = 0.f, cy0 = 0.f, cx1 = 0.f, cy1 = 0.f, cx2 = 0.f, cy2 = 0.f;
        float cx3 = 0.f, cy3 = 0.f, cx4 = 0.f, cy4 = 0.f, cx5 = 0.f, cy5 = 0.f;

        // --- phase 0: streams over groups {0,2,4}; g4 via VMEM if enabled
        {
            int n0 = __popc(ga[0]) > __popc(gb[0]) ? __popc(ga[0]) : __popc(gb[0]);
            int n2g = __popc(ga[2]) > __popc(gb[2]) ? __popc(ga[2]) : __popc(gb[2]);
            int n4 = __popc(ga[4]) > __popc(gb[4]) ? __popc(ga[4]) : __popc(gb[4]);
            int n = n0 > n2g ? n0 : n2g;
            n = n > n4 ? n : n4;
            for (; n > 0; --n) {
                int f0 = v_ffbl(vm0); vm0 &= vm0 - 1;
                int f2 = v_ffbl(vm2); vm2 &= vm2 - 1;
                int f4 = v_ffbl(vm4); vm4 &= vm4 - 1;
                float2 w4 = *(const float2*)(gbase4 + f4 * 64);  // VMEM (or LDS)
                float2 w0 = *(const float2*)(gbase0 + f0 * 64);
                float2 w2 = *(const float2*)(gbase2 + f2 * 64);
                cx0 += w0.x; cy0 += w0.y;
                cx2 += w2.x; cy2 += w2.y;
                cx4 += w4.x; cy4 += w4.y;
            }
        }
        // --- phase 1: streams over groups {1,3,5}; g5 via VMEM if enabled
        {
            int n1 = __popc(ga[1]) > __popc(gb[1]) ? __popc(ga[1]) : __popc(gb[1]);
            int n3 = __popc(ga[3]) > __popc(gb[3]) ? __popc(ga[3]) : __popc(gb[3]);
            int n5 = __popc(ga[5]) > __popc(gb[5]) ? __popc(ga[5]) : __popc(gb[5]);
            int n = n1 > n3 ? n1 : n3;
            n = n > n5 ? n : n5;
            for (; n > 0; --n) {
                int f1 = v_ffbl(vm1); vm1 &= vm1 - 1;
                int f3 = v_ffbl(vm3); vm3 &= vm3 - 1;
                int f5 = v_ffbl(vm5); vm5 &= vm5 - 1;
                float2 w5 = *(const float2*)(gbase5 + f5 * 64);  // VMEM (or LDS)
                float2 w1 = *(const float2*)(gbase1 + f1 * 64);
                float2 w3 = *(const float2*)(gbase3 + f3 * 64);
                cx1 += w1.x; cy1 += w1.y;
                cx3 += w3.x; cy3 += w3.y;
                cx5 += w5.x; cy5 += w5.y;
            }
        }

        // Merge partials in ascending-d block order
        float cx = ((((cx0 + cx1) + cx2) + cx3) + cx4) + cx5;
        float cy = ((((cy0 + cy1) + cy2) + cy3) + cy4) + cy5;
        float c1x = cx, c1y = cy;                      // step t   (lanes 0..24)
        float c2x = __shfl_down(cx, 32);               // step t+1 -> lanes 0..24
        float c2y = __shfl_down(cy, 32);

        // --- LIF layer 1, step t
        mem1x = 0.9f * mem1x + c1x;
        bool spx = (mem1x - 1.0f > 0.f) && (lane < 25);
        mem1x -= spx ? 1.0f : 0.f;
        mem1y = 0.9f * mem1y + c1y;
        bool spy = (mem1y - 1.0f > 0.f) && (lane < 25);
        mem1y -= spy ? 1.0f : 0.f;
        unsigned int lo_t = (unsigned int)(__ballot(spx) & 0x1FFFFFFull); // h<25
        unsigned int hi_t = (unsigned int)(__ballot(spy) & 0x1FFFFFFull); // h>=25
        // --- LIF layer 1, step t+1
        mem1x = 0.9f * mem1x + c2x;
        bool qx = (mem1x - 1.0f > 0.f) && (lane < 25);
        mem1x -= qx ? 1.0f : 0.f;
        mem1y = 0.9f * mem1y + c2y;
        bool qy = (mem1y - 1.0f > 0.f) && (lane < 25);
        mem1y -= qy ? 1.0f : 0.f;
        unsigned int lo_u = (unsigned int)(__ballot(qx) & 0x1FFFFFFull);
        unsigned int hi_u = (unsigned int)(__ballot(qy) & 0x1FFFFFFull);

        // --- layer-2 quarter-wave gather: q0..q3 scan {lo_t,hi_t,lo_u,hi_u};
        //     one ds_read_b32 per trip covers 4 spikes; f=-1 -> zero row.
        int p0 = __popc(lo_t), p1 = __popc(hi_t), p2 = __popc(lo_u), p3 = __popc(hi_u);
        int n2 = p0 > p1 ? p0 : p1;
        n2 = n2 > p2 ? n2 : p2;
        n2 = n2 > p3 ? n2 : p3;
        float cq = 0.f;
        if (n2) {
            unsigned int vmq = isLo ? (hiQ ? hi_t : lo_t) : (hiQ ? hi_u : lo_u);
            for (; n2 > 0; --n2) {
                int f = v_ffbl(vmq); vmq &= vmq - 1;
                cq += *(base2 + f * 16);
            }
        }
        // combine quarters: lanes 0..4 get (lo+hi) for t; +32 lanes for t+1
        float tmp = cq + __shfl_down(cq, 16);
        float cur2 = tmp;                              // step t   (lanes 0..4)
        float c2t1 = __shfl_down(tmp, 32);             // step t+1 -> lanes 0..4

        // --- LIF layer 2, step t
        mem2 = 0.9f * mem2 + cur2;
        bool sp2 = (mem2 - 1.0f > 0.f);
        mem2 -= sp2 ? 1.0f : 0.f;
        if (active && lane < C)
            outSpk[(size_t)t * B * C + (size_t)b * C + lane] = sp2 ? 1.0f : 0.0f;
        // --- LIF layer 2, step t+1
        mem2 = 0.9f * mem2 + c2t1;
        bool sp2b = (mem2 - 1.0f > 0.f);
        mem2 -= sp2b ? 1.0f : 0.f;
        if (active && lane < C)
            outSpk[(size_t)(t + 1) * B * C + (size_t)b * C + lane] = sp2b ? 1.0f : 0.0f;
    }

    // --- reduce spike count across the wave, write counts[b]
    for (int o = 32; o; o >>= 1) cnt += __shfl_xor(cnt, o, 64);
    if (active && lane == 0) outCnt[b] = (float)cnt;
}

extern "C" void kernel_launch(void* const* d_in, const int* in_sizes, int n_in,
                              void* d_out, int out_size, void* d_ws, size_t ws_size,
                              hipStream_t stream) {
    const float* x  = (const float*)d_in[0];
    const float* W1 = (const float*)d_in[1];
    const float* W2 = (const float*)d_in[2];
    float* out = (float*)d_out;
    const int B = in_sizes[0] / D;
    const int blocks = (B + WPB - 1) / WPB;

    if (ws_size >= (size_t)WG_BYTES) {
        float* Wg = (float*)d_ws;
        prep_wg<<<(ROWS1 * RS + 1023) / 1024, 1024, 0, stream>>>(W1, Wg);
        burst_snn_kernel<true><<<blocks, 1024, 0, stream>>>(x, W1, W2, Wg, out, B);
    } else {
        burst_snn_kernel<false><<<blocks, 1024, 0, stream>>>(x, W1, W2, nullptr, out, B);
    }
}

// Round 11
// 162.227 us; speedup vs baseline: 1.0593x; 1.0593x over previous
//
#include <hip/hip_runtime.h>

// BurstSnn: 32-step burst-encoder + 2-layer LIF SNN, B=16384, D=187, H=50, C=5.
// One wave per batch element; 16 waves/block share one LDS weight copy.
// R10 = R8 (best, 115us) + latency-slack filling, arithmetic unchanged:
//  (1) encoder software-pipelined: pair p+1 masks computed BEFORE pair p's
//      gather (independent VALU chain fills the wave's own LDS-wait slack);
//  (2) gather loops hand-unrolled x2: 6 independent ds_read_b64 in flight
//      per iteration, halved loop control; odd trip peeled (uniform branch).
// Within-accumulator order stays ascending-d (a then b) -> bit-identical.
// L1: 2 phases x 3 streams (groups {0,2,4}/{1,3,5}), half-wave t/t+1 pairing,
// float2 rows {h=l, h=l+25}, zero rows at rd=33g absorb exhausted streams.
// L2: quarter-wave gather (q0..q3 = {lo_t, hi_t, lo_u, hi_u}).

constexpr int D = 187;
constexpr int H = 50;
constexpr int C = 5;
constexpr int T = 32;
constexpr int WPB = 16;        // waves per block
constexpr int ROWS1 = 193;     // rows rd = 33*(d>>5) + (d&31) + 1; rd=33g zero
constexpr int RS = 64;         // floats per Wt1 row (256 B)

__device__ __forceinline__ int v_ffbl(unsigned int m) {  // -1 when m == 0
    int r;
    asm("v_ffbl_b32 %0, %1" : "=v"(r) : "v"(m));
    return r;
}

__global__ __launch_bounds__(1024, 8)
void burst_snn_kernel(const float* __restrict__ x,
                      const float* __restrict__ W1,
                      const float* __restrict__ W2,
                      float* __restrict__ out, int B) {
    // Wt1 row layout (split-pair): floats {2l,2l+1} = {W[h=l], W[h=l+25]}, l<25.
    __shared__ float Wt1[ROWS1 * RS];   // 12352 floats = 48.25 KB
    // Wt2: 64 rows x 16 floats. row 0: zeros; rows 1..25: h=0..24;
    // row 26: zeros; rows 27..51: h=25..49; rest zeros. cols 5..15 zero pad.
    __shared__ float Wt2[1024];         // 4 KB

    const int tid = threadIdx.x;
    for (int idx = tid; idx < ROWS1 * RS; idx += 1024) {
        int rd = idx >> 6, j = idx & 63;
        int g = rd / 33;
        bool zrow = (rd == 33 * g);
        int d = rd - 1 - g;
        int l = j >> 1;
        int h = (j & 1) ? (l + 25) : l;
        float v = 0.f;
        if (!zrow && l < 25) v = W1[h * D + d];
        Wt1[idx] = v;
    }
    {
        int r = tid >> 4, c = tid & 15;   // tid covers all 1024
        int h = -1;
        if (r >= 1 && r <= 25) h = r - 1;
        else if (r >= 27 && r <= 51) h = r - 2;
        float v = 0.f;
        if (h >= 0 && c < C) v = W2[c * H + h];
        Wt2[tid] = v;
    }
    __syncthreads();

    const int lane = tid & 63;
    const int b = blockIdx.x * WPB + (tid >> 6);
    const bool active = b < B;
    const bool isLo = lane < 32;
    const int laneHalf = lane & 31;
    const int laneOff2 = laneHalf * 2;   // float2 slot within a Wt1 row

    // L1 per-group base pointers, +1 row folded in: addr(f) = base + f*64;
    // f = -1 (exhausted stream) -> zero row 33g.
    const float* gbase0 = Wt1 + ((33 * 0 + 1) << 6) + laneOff2;
    const float* gbase1 = Wt1 + ((33 * 1 + 1) << 6) + laneOff2;
    const float* gbase2 = Wt1 + ((33 * 2 + 1) << 6) + laneOff2;
    const float* gbase3 = Wt1 + ((33 * 3 + 1) << 6) + laneOff2;
    const float* gbase4 = Wt1 + ((33 * 4 + 1) << 6) + laneOff2;
    const float* gbase5 = Wt1 + ((33 * 5 + 1) << 6) + laneOff2;

    // L2 quarter-wave setup: quarter q = lane>>4 scans {lo_t,hi_t,lo_u,hi_u}.
    const int q = lane >> 4;
    const bool hiQ = (q & 1) != 0;
    const float* base2 = Wt2 + ((hiQ ? 27 : 1) << 4) + (lane & 15);

    // Encoder registers: dims lane, lane+64, lane+128 (3rd valid for lane<59)
    float r0 = 0.f, r1 = 0.f, r2 = 0.f;
    if (active) {
        const float* xb = x + (size_t)b * D;
        r0 = xb[lane];
        r1 = xb[64 + lane];
        if (lane < D - 128) r2 = xb[128 + lane];
    }
    float th0 = 0.125f, th1 = 0.125f, th2 = 0.125f;
    float mem1x = 0.f, mem1y = 0.f;  // lanes 0..24: h = lane / h = lane+25
    float mem2 = 0.f;                // lanes 0..4: c = lane
    int cnt = 0;

    float* outSpk = out;                     // [T][B][C]
    float* outCnt = out + (size_t)T * B * C; // [B]

    unsigned int ga[6], gb[6];

    // --- encoder pair: two exact fp32 steps; masks for (t, t+1) into A/Bm
    auto enc_pair = [&]() {
        {
            bool s0 = r0 >= th0, s1 = r1 >= th1, s2 = r2 >= th2;
            r0 -= s0 ? th0 : 0.f; th0 = s0 ? th0 + th0 : 0.125f;
            r1 -= s1 ? th1 : 0.f; th1 = s1 ? th1 + th1 : 0.125f;
            r2 -= s2 ? th2 : 0.f; th2 = s2 ? th2 + th2 : 0.125f;
            cnt += (int)s0 + (int)s1 + (int)s2;
            unsigned long long B0 = __ballot(s0), B1 = __ballot(s1), B2 = __ballot(s2);
            ga[0] = (unsigned int)B0; ga[1] = (unsigned int)(B0 >> 32);
            ga[2] = (unsigned int)B1; ga[3] = (unsigned int)(B1 >> 32);
            ga[4] = (unsigned int)B2; ga[5] = (unsigned int)(B2 >> 32);
        }
        {
            bool s0 = r0 >= th0, s1 = r1 >= th1, s2 = r2 >= th2;
            r0 -= s0 ? th0 : 0.f; th0 = s0 ? th0 + th0 : 0.125f;
            r1 -= s1 ? th1 : 0.f; th1 = s1 ? th1 + th1 : 0.125f;
            r2 -= s2 ? th2 : 0.f; th2 = s2 ? th2 + th2 : 0.125f;
            cnt += (int)s0 + (int)s1 + (int)s2;
            unsigned long long B0 = __ballot(s0), B1 = __ballot(s1), B2 = __ballot(s2);
            gb[0] = (unsigned int)B0; gb[1] = (unsigned int)(B0 >> 32);
            gb[2] = (unsigned int)B1; gb[3] = (unsigned int)(B1 >> 32);
            gb[4] = (unsigned int)B2; gb[5] = (unsigned int)(B2 >> 32);
        }
    };

    enc_pair();   // prologue: masks for pair 0

    for (int t = 0; t < T; t += 2) {
        // Snapshot current pair's per-lane masks + trip counts
        unsigned int vm0 = isLo ? ga[0] : gb[0];
        unsigned int vm1 = isLo ? ga[1] : gb[1];
        unsigned int vm2 = isLo ? ga[2] : gb[2];
        unsigned int vm3 = isLo ? ga[3] : gb[3];
        unsigned int vm4 = isLo ? ga[4] : gb[4];
        unsigned int vm5 = isLo ? ga[5] : gb[5];
        int m0 = __popc(ga[0]) > __popc(gb[0]) ? __popc(ga[0]) : __popc(gb[0]);
        int m1 = __popc(ga[1]) > __popc(gb[1]) ? __popc(ga[1]) : __popc(gb[1]);
        int m2 = __popc(ga[2]) > __popc(gb[2]) ? __popc(ga[2]) : __popc(gb[2]);
        int m3 = __popc(ga[3]) > __popc(gb[3]) ? __popc(ga[3]) : __popc(gb[3]);
        int m4 = __popc(ga[4]) > __popc(gb[4]) ? __popc(ga[4]) : __popc(gb[4]);
        int m5 = __popc(ga[5]) > __popc(gb[5]) ? __popc(ga[5]) : __popc(gb[5]);

        // Pipeline: compute NEXT pair's masks now (independent VALU filler)
        if (t + 2 < T) enc_pair();

        float cx0 = 0.f, cy0 = 0.f, cx1 = 0.f, cy1 = 0.f, cx2 = 0.f, cy2 = 0.f;
        float cx3 = 0.f, cy3 = 0.f, cx4 = 0.f, cy4 = 0.f, cx5 = 0.f, cy5 = 0.f;

        // --- phase 0: streams over groups {0,2,4}, unrolled x2
        {
            int n = m0 > m2 ? m0 : m2;
            n = n > m4 ? n : m4;
            for (; n >= 2; n -= 2) {
                int f0a = v_ffbl(vm0); vm0 &= vm0 - 1;
                int f0b = v_ffbl(vm0); vm0 &= vm0 - 1;
                int f2a = v_ffbl(vm2); vm2 &= vm2 - 1;
                int f2b = v_ffbl(vm2); vm2 &= vm2 - 1;
                int f4a = v_ffbl(vm4); vm4 &= vm4 - 1;
                int f4b = v_ffbl(vm4); vm4 &= vm4 - 1;
                float2 w0a = *(const float2*)(gbase0 + f0a * 64);
                float2 w2a = *(const float2*)(gbase2 + f2a * 64);
                float2 w4a = *(const float2*)(gbase4 + f4a * 64);
                float2 w0b = *(const float2*)(gbase0 + f0b * 64);
                float2 w2b = *(const float2*)(gbase2 + f2b * 64);
                float2 w4b = *(const float2*)(gbase4 + f4b * 64);
                cx0 += w0a.x; cy0 += w0a.y; cx0 += w0b.x; cy0 += w0b.y;
                cx2 += w2a.x; cy2 += w2a.y; cx2 += w2b.x; cy2 += w2b.y;
                cx4 += w4a.x; cy4 += w4a.y; cx4 += w4b.x; cy4 += w4b.y;
            }
            if (n == 1) {
                int f0 = v_ffbl(vm0); vm0 &= vm0 - 1;
                int f2 = v_ffbl(vm2); vm2 &= vm2 - 1;
                int f4 = v_ffbl(vm4); vm4 &= vm4 - 1;
                float2 w0 = *(const float2*)(gbase0 + f0 * 64);
                float2 w2 = *(const float2*)(gbase2 + f2 * 64);
                float2 w4 = *(const float2*)(gbase4 + f4 * 64);
                cx0 += w0.x; cy0 += w0.y;
                cx2 += w2.x; cy2 += w2.y;
                cx4 += w4.x; cy4 += w4.y;
            }
        }
        // --- phase 1: streams over groups {1,3,5}, unrolled x2
        {
            int n = m1 > m3 ? m1 : m3;
            n = n > m5 ? n : m5;
            for (; n >= 2; n -= 2) {
                int f1a = v_ffbl(vm1); vm1 &= vm1 - 1;
                int f1b = v_ffbl(vm1); vm1 &= vm1 - 1;
                int f3a = v_ffbl(vm3); vm3 &= vm3 - 1;
                int f3b = v_ffbl(vm3); vm3 &= vm3 - 1;
                int f5a = v_ffbl(vm5); vm5 &= vm5 - 1;
                int f5b = v_ffbl(vm5); vm5 &= vm5 - 1;
                float2 w1a = *(const float2*)(gbase1 + f1a * 64);
                float2 w3a = *(const float2*)(gbase3 + f3a * 64);
                float2 w5a = *(const float2*)(gbase5 + f5a * 64);
                float2 w1b = *(const float2*)(gbase1 + f1b * 64);
                float2 w3b = *(const float2*)(gbase3 + f3b * 64);
                float2 w5b = *(const float2*)(gbase5 + f5b * 64);
                cx1 += w1a.x; cy1 += w1a.y; cx1 += w1b.x; cy1 += w1b.y;
                cx3 += w3a.x; cy3 += w3a.y; cx3 += w3b.x; cy3 += w3b.y;
                cx5 += w5a.x; cy5 += w5a.y; cx5 += w5b.x; cy5 += w5b.y;
            }
            if (n == 1) {
                int f1 = v_ffbl(vm1); vm1 &= vm1 - 1;
                int f3 = v_ffbl(vm3); vm3 &= vm3 - 1;
                int f5 = v_ffbl(vm5); vm5 &= vm5 - 1;
                float2 w1 = *(const float2*)(gbase1 + f1 * 64);
                float2 w3 = *(const float2*)(gbase3 + f3 * 64);
                float2 w5 = *(const float2*)(gbase5 + f5 * 64);
                cx1 += w1.x; cy1 += w1.y;
                cx3 += w3.x; cy3 += w3.y;
                cx5 += w5.x; cy5 += w5.y;
            }
        }

        // Merge partials in ascending-d block order
        float cx = ((((cx0 + cx1) + cx2) + cx3) + cx4) + cx5;
        float cy = ((((cy0 + cy1) + cy2) + cy3) + cy4) + cy5;
        float c1x = cx, c1y = cy;                      // step t   (lanes 0..24)
        float c2x = __shfl_down(cx, 32);               // step t+1 -> lanes 0..24
        float c2y = __shfl_down(cy, 32);

        // --- LIF layer 1, step t
        mem1x = 0.9f * mem1x + c1x;
        bool spx = (mem1x - 1.0f > 0.f) && (lane < 25);
        mem1x -= spx ? 1.0f : 0.f;
        mem1y = 0.9f * mem1y + c1y;
        bool spy = (mem1y - 1.0f > 0.f) && (lane < 25);
        mem1y -= spy ? 1.0f : 0.f;
        unsigned int lo_t = (unsigned int)(__ballot(spx) & 0x1FFFFFFull); // h<25
        unsigned int hi_t = (unsigned int)(__ballot(spy) & 0x1FFFFFFull); // h>=25
        // --- LIF layer 1, step t+1
        mem1x = 0.9f * mem1x + c2x;
        bool qx = (mem1x - 1.0f > 0.f) && (lane < 25);
        mem1x -= qx ? 1.0f : 0.f;
        mem1y = 0.9f * mem1y + c2y;
        bool qy = (mem1y - 1.0f > 0.f) && (lane < 25);
        mem1y -= qy ? 1.0f : 0.f;
        unsigned int lo_u = (unsigned int)(__ballot(qx) & 0x1FFFFFFull);
        unsigned int hi_u = (unsigned int)(__ballot(qy) & 0x1FFFFFFull);

        // --- layer-2 quarter-wave gather, unrolled x2:
        //     q0..q3 scan {lo_t,hi_t,lo_u,hi_u}; f=-1 -> zero row.
        int p0 = __popc(lo_t), p1 = __popc(hi_t), p2 = __popc(lo_u), p3 = __popc(hi_u);
        int n2 = p0 > p1 ? p0 : p1;
        n2 = n2 > p2 ? n2 : p2;
        n2 = n2 > p3 ? n2 : p3;
        float cq = 0.f;
        unsigned int vmq = isLo ? (hiQ ? hi_t : lo_t) : (hiQ ? hi_u : lo_u);
        for (; n2 >= 2; n2 -= 2) {
            int fa = v_ffbl(vmq); vmq &= vmq - 1;
            int fb = v_ffbl(vmq); vmq &= vmq - 1;
            float wa = *(base2 + fa * 16);
            float wb = *(base2 + fb * 16);
            cq += wa;
            cq += wb;
        }
        if (n2 == 1) {
            int f = v_ffbl(vmq); vmq &= vmq - 1;
            cq += *(base2 + f * 16);
        }
        // combine quarters: lanes 0..4 get (lo+hi) for t; +32 lanes for t+1
        float tmp = cq + __shfl_down(cq, 16);
        float cur2 = tmp;                              // step t   (lanes 0..4)
        float c2t1 = __shfl_down(tmp, 32);             // step t+1 -> lanes 0..4

        // --- LIF layer 2, step t
        mem2 = 0.9f * mem2 + cur2;
        bool sp2 = (mem2 - 1.0f > 0.f);
        mem2 -= sp2 ? 1.0f : 0.f;
        if (active && lane < C)
            outSpk[(size_t)t * B * C + (size_t)b * C + lane] = sp2 ? 1.0f : 0.0f;
        // --- LIF layer 2, step t+1
        mem2 = 0.9f * mem2 + c2t1;
        bool sp2b = (mem2 - 1.0f > 0.f);
        mem2 -= sp2b ? 1.0f : 0.f;
        if (active && lane < C)
            outSpk[(size_t)(t + 1) * B * C + (size_t)b * C + lane] = sp2b ? 1.0f : 0.0f;
    }

    // --- reduce spike count across the wave, write counts[b]
    for (int o = 32; o; o >>= 1) cnt += __shfl_xor(cnt, o, 64);
    if (active && lane == 0) outCnt[b] = (float)cnt;
}

extern "C" void kernel_launch(void* const* d_in, const int* in_sizes, int n_in,
                              void* d_out, int out_size, void* d_ws, size_t ws_size,
                              hipStream_t stream) {
    const float* x  = (const float*)d_in[0];
    const float* W1 = (const float*)d_in[1];
    const float* W2 = (const float*)d_in[2];
    float* out = (float*)d_out;
    const int B = in_sizes[0] / D;
    const int blocks = (B + WPB - 1) / WPB;
    burst_snn_kernel<<<blocks, 1024, 0, stream>>>(x, W1, W2, out, B);
}